// Round 11
// baseline (125.874 us; speedup 1.0000x reference)
//
#include <hip/hip_runtime.h>
#include <hip/hip_bf16.h>

#define B_ 32
#define N_ 128
#define D_ 512
#define A_ 512
#define R_ (B_*N_)     // 4096 rows
#define OC 1024        // fused Y cols (E1 | E2)
#define CEXP 2.8853900817779268f   // 2*log2(e)

typedef __attribute__((ext_vector_type(8)))  short frag_ab;   // 8 bf16
typedef __attribute__((ext_vector_type(16))) float frag_c;    // 16 f32 (32x32 acc)

__device__ inline unsigned pack2bf(float a, float b) {
    unsigned ua = __builtin_bit_cast(unsigned, a) + 0x8000u;
    unsigned ub = __builtin_bit_cast(unsigned, b) + 0x8000u;
    return __builtin_amdgcn_perm(ub, ua, 0x07060302);
}
__device__ inline float bf2f_lo(unsigned u){ return __builtin_bit_cast(float, u << 16); }
__device__ inline float bf2f_hi(unsigned u){ return __builtin_bit_cast(float, u & 0xffff0000u); }

// ---------------- Kernel 1: Yb = bf16(exp2(C*(X*[W1;W2]^T + [b1;b2]))) ----
// Fused fp32->bf16 cvt in staging (no k0). 64x64 tile, BK=64, 4 waves each
// one 32x32x16-MFMA acc. Grid 1024 = 4 blk/CU. LDS [64 rows][8 slots x16B],
// phys_slot = slot ^ (row&7) both sides (R10-verified).
__global__ __launch_bounds__(256) void k1_mfma(
    const float* __restrict__ X,
    const float* __restrict__ W1, const float* __restrict__ b1,
    const float* __restrict__ W2, const float* __restrict__ b2,
    unsigned short* __restrict__ Yb)
{
    __shared__ unsigned short As[2][64*64];
    __shared__ unsigned short Bs[2][64*64];

    const int t = threadIdx.x, lane = t&63, wid = t>>6;
    const int wr = wid>>1, wc = wid&1;
    const int row0 = blockIdx.x*64, col0 = blockIdx.y*64;
    const float* Wb = (col0 < A_) ? W1 : W2;
    const float* bb = (col0 < A_) ? b1 : b2;
    const int wrow0 = col0 & (A_-1);

    const int sr = t>>2;          // staging row 0..63
    const int ss = (t&3)*2;       // staging slots: ss, ss+1 (8 elems each)
    const int sf = sr & 7;        // write-side XOR key

    frag_c acc;
#pragma unroll
    for (int r=0;r<16;++r) acc[r] = 0.f;

    const int fr = lane & 31;
    const int hs = lane >> 5;              // k-half within 16-k group
    const int arow = wr*32 + fr, af_f = arow & 7;
    const int brow = wc*32 + fr, bf_f = brow & 7;

    const float* pxb = &X [(size_t)(row0 +sr)*D_ + ss*8];
    const float* pwb = &Wb[(size_t)(wrow0+sr)*D_ + ss*8];

    { // prologue: stage K-chunk 0 into buf0
        float4 x0 = *(const float4*)pxb,     x1 = *(const float4*)(pxb+4);
        float4 x2 = *(const float4*)(pxb+8), x3 = *(const float4*)(pxb+12);
        float4 w0 = *(const float4*)pwb,     w1 = *(const float4*)(pwb+4);
        float4 w2 = *(const float4*)(pwb+8), w3 = *(const float4*)(pwb+12);
        uint4 A0 = {pack2bf(x0.x,x0.y), pack2bf(x0.z,x0.w), pack2bf(x1.x,x1.y), pack2bf(x1.z,x1.w)};
        uint4 A1 = {pack2bf(x2.x,x2.y), pack2bf(x2.z,x2.w), pack2bf(x3.x,x3.y), pack2bf(x3.z,x3.w)};
        uint4 B0 = {pack2bf(w0.x,w0.y), pack2bf(w0.z,w0.w), pack2bf(w1.x,w1.y), pack2bf(w1.z,w1.w)};
        uint4 B1 = {pack2bf(w2.x,w2.y), pack2bf(w2.z,w2.w), pack2bf(w3.x,w3.y), pack2bf(w3.z,w3.w)};
        *(uint4*)&As[0][sr*64 + (( ss   ^sf)<<3)] = A0;
        *(uint4*)&As[0][sr*64 + (((ss+1)^sf)<<3)] = A1;
        *(uint4*)&Bs[0][sr*64 + (( ss   ^sf)<<3)] = B0;
        *(uint4*)&Bs[0][sr*64 + (((ss+1)^sf)<<3)] = B1;
    }
    __syncthreads();

#pragma unroll
    for (int s = 0; s < 8; ++s) {
        const int cur = s & 1;
        float4 x0,x1,x2,x3,w0,w1,w2,w3;
        if (s < 7) {   // early-issue next K-chunk's loads (fp32)
            const int k0 = (s+1)*64;
            x0 = *(const float4*)(pxb+k0);    x1 = *(const float4*)(pxb+k0+4);
            x2 = *(const float4*)(pxb+k0+8);  x3 = *(const float4*)(pxb+k0+12);
            w0 = *(const float4*)(pwb+k0);    w1 = *(const float4*)(pwb+k0+4);
            w2 = *(const float4*)(pwb+k0+8);  w3 = *(const float4*)(pwb+k0+12);
        }
        frag_ab af[4], bf[4];
#pragma unroll
        for (int ks=0; ks<4; ++ks) {
            const int slot = ks*2 + hs;
            af[ks] = *(const frag_ab*)&As[cur][arow*64 + ((slot^af_f)<<3)];
            bf[ks] = *(const frag_ab*)&Bs[cur][brow*64 + ((slot^bf_f)<<3)];
        }
#pragma unroll
        for (int ks=0; ks<4; ++ks)
            acc = __builtin_amdgcn_mfma_f32_32x32x16_bf16(af[ks], bf[ks], acc, 0, 0, 0);
        if (s < 7) {   // pack + write-late into the other buffer
            uint4 A0 = {pack2bf(x0.x,x0.y), pack2bf(x0.z,x0.w), pack2bf(x1.x,x1.y), pack2bf(x1.z,x1.w)};
            uint4 A1 = {pack2bf(x2.x,x2.y), pack2bf(x2.z,x2.w), pack2bf(x3.x,x3.y), pack2bf(x3.z,x3.w)};
            uint4 B0 = {pack2bf(w0.x,w0.y), pack2bf(w0.z,w0.w), pack2bf(w1.x,w1.y), pack2bf(w1.z,w1.w)};
            uint4 B1 = {pack2bf(w2.x,w2.y), pack2bf(w2.z,w2.w), pack2bf(w3.x,w3.y), pack2bf(w3.z,w3.w)};
            *(uint4*)&As[cur^1][sr*64 + (( ss   ^sf)<<3)] = A0;
            *(uint4*)&As[cur^1][sr*64 + (((ss+1)^sf)<<3)] = A1;
            *(uint4*)&Bs[cur^1][sr*64 + (( ss   ^sf)<<3)] = B0;
            *(uint4*)&Bs[cur^1][sr*64 + (((ss+1)^sf)<<3)] = B1;
        }
        __syncthreads();
    }

    // epilogue: 32x32 C/D layout col=lane&31, row=(reg&3)+8*(reg>>2)+4*(lane>>5)
    const int cc = col0 + wc*32 + (lane&31);
    const float bias = bb[cc & (A_-1)];
    const int rbase = row0 + wr*32 + 4*(lane>>5);
#pragma unroll
    for (int r=0; r<16; ++r) {
        const int rr = rbase + (r&3) + 8*(r>>2);
        float e = __builtin_amdgcn_exp2f(CEXP*(acc[r] + bias));
        Yb[(size_t)rr*OC + cc] =
            (unsigned short)((__builtin_bit_cast(unsigned, e) + 0x8000u) >> 16);
    }
}

// ---------------- Kernel 2 ----------------
// out[b,i,j] = wsum - 2*sum_a wo[a]/(1+E1[j,a]*E2[i+1,a]) + bout
// Block: 32j x 32i x FULL 512a. ONE barrier, no chunk loop, direct out write.
// bf16 LDS tiles (66 KB): e1s/e2s [32 rows][64 slots x16B],
// phys_slot = slot ^ (row>>1): staged writes and paired-row reads <=2-way.
// 2x2 per thread, reciprocal pairing: w0/r+w1/s = (w0*s+w1*r)*rcp(r*s).
__global__ __launch_bounds__(256) void k2_tanh(
    const unsigned short* __restrict__ Yb,
    const float* __restrict__ Wout, const float* __restrict__ bout,
    float* __restrict__ out)
{
    __shared__ unsigned short e1s[32*512];
    __shared__ unsigned short e2s[32*512];
    __shared__ float wo[A_];
    __shared__ float wsum_s[4];

    const int t  = threadIdx.x;
    const int jt = blockIdx.x & 3;
    const int it = blockIdx.x >> 2;
    const int b  = blockIdx.y;

    {   // Wout -> LDS + block sum
        float w0 = Wout[t], w1 = Wout[256+t];
        wo[t] = w0; wo[256+t] = w1;
        float s = w0 + w1;
#pragma unroll
        for (int off=32; off>=1; off>>=1) s += __shfl_down(s, off, 64);
        if ((t&63)==0) wsum_s[t>>6] = s;
    }

    const unsigned short* yb = Yb + (size_t)b*N_*OC;
    {   // stage E1/E2 (bf16, swizzled): row r = t>>3, 8 slots per thread
        const int r = t>>3, inner = t&7;
        const int key = r >> 1;                 // 0..15
        const int g2 = min(it*32 + r + 1, 127);
        const unsigned short* p1 = &yb[(size_t)(jt*32 + r)*OC + inner*8];
        const unsigned short* p2 = &yb[(size_t)g2*OC + A_ + inner*8];
        unsigned short* d1 = &e1s[r*512];
        unsigned short* d2 = &e2s[r*512];
#pragma unroll
        for (int q=0; q<8; ++q) {
            const int slot = q*8 + inner;
            uint4 v1 = *(const uint4*)(p1 + q*64);
            uint4 v2 = *(const uint4*)(p2 + q*64);
            *(uint4*)&d1[(slot^key)<<3] = v1;
            *(uint4*)&d2[(slot^key)<<3] = v2;
        }
    }
    __syncthreads();

    const int jl = t&15, il = t>>4;
    const unsigned short* ru0 = &e1s[(2*jl  )*512];
    const unsigned short* ru1 = &e1s[(2*jl+1)*512];
    const unsigned short* rv0 = &e2s[(2*il  )*512];
    const unsigned short* rv1 = &e2s[(2*il+1)*512];

    float a00=0.f, a01=0.f, a10=0.f, a11=0.f;   // a[joff][ioff]

#pragma unroll 2
    for (int c8=0; c8<64; ++c8) {
        uint4 U0 = *(const uint4*)&ru0[(c8^jl)<<3];
        uint4 U1 = *(const uint4*)&ru1[(c8^jl)<<3];
        uint4 V0 = *(const uint4*)&rv0[(c8^il)<<3];
        uint4 V1 = *(const uint4*)&rv1[(c8^il)<<3];
        float4 wa = *(const float4*)&wo[c8*8];
        float4 wb = *(const float4*)&wo[c8*8+4];
        float u0[8], u1[8], v0[8], v1[8];
        u0[0]=bf2f_lo(U0.x); u0[1]=bf2f_hi(U0.x); u0[2]=bf2f_lo(U0.y); u0[3]=bf2f_hi(U0.y);
        u0[4]=bf2f_lo(U0.z); u0[5]=bf2f_hi(U0.z); u0[6]=bf2f_lo(U0.w); u0[7]=bf2f_hi(U0.w);
        u1[0]=bf2f_lo(U1.x); u1[1]=bf2f_hi(U1.x); u1[2]=bf2f_lo(U1.y); u1[3]=bf2f_hi(U1.y);
        u1[4]=bf2f_lo(U1.z); u1[5]=bf2f_hi(U1.z); u1[6]=bf2f_lo(U1.w); u1[7]=bf2f_hi(U1.w);
        v0[0]=bf2f_lo(V0.x); v0[1]=bf2f_hi(V0.x); v0[2]=bf2f_lo(V0.y); v0[3]=bf2f_hi(V0.y);
        v0[4]=bf2f_lo(V0.z); v0[5]=bf2f_hi(V0.z); v0[6]=bf2f_lo(V0.w); v0[7]=bf2f_hi(V0.w);
        v1[0]=bf2f_lo(V1.x); v1[1]=bf2f_hi(V1.x); v1[2]=bf2f_lo(V1.y); v1[3]=bf2f_hi(V1.y);
        v1[4]=bf2f_lo(V1.z); v1[5]=bf2f_hi(V1.z); v1[6]=bf2f_lo(V1.w); v1[7]=bf2f_hi(V1.w);
        float wf[8] = {wa.x, wa.y, wa.z, wa.w, wb.x, wb.y, wb.z, wb.w};
#pragma unroll
        for (int p=0; p<4; ++p) {
            const int e0 = 2*p, e1 = 2*p+1;
            { float r=fmaf(u0[e0],v0[e0],1.f), s=fmaf(u0[e1],v0[e1],1.f);
              a00 = fmaf(fmaf(wf[e0],s,wf[e1]*r), __builtin_amdgcn_rcpf(r*s), a00); }
            { float r=fmaf(u1[e0],v0[e0],1.f), s=fmaf(u1[e1],v0[e1],1.f);
              a10 = fmaf(fmaf(wf[e0],s,wf[e1]*r), __builtin_amdgcn_rcpf(r*s), a10); }
            { float r=fmaf(u0[e0],v1[e0],1.f), s=fmaf(u0[e1],v1[e1],1.f);
              a01 = fmaf(fmaf(wf[e0],s,wf[e1]*r), __builtin_amdgcn_rcpf(r*s), a01); }
            { float r=fmaf(u1[e0],v1[e0],1.f), s=fmaf(u1[e1],v1[e1],1.f);
              a11 = fmaf(fmaf(wf[e0],s,wf[e1]*r), __builtin_amdgcn_rcpf(r*s), a11); }
        }
    }

    const float base = wsum_s[0]+wsum_s[1]+wsum_s[2]+wsum_s[3] + bout[0];
    const int i0 = it*32 + 2*il;      // even, <=126: always valid
    const int j0 = jt*32 + 2*jl;
    float* ob = out + (size_t)b*127*128;
    *(float2*)&ob[i0*128 + j0] = float2{base - 2.f*a00, base - 2.f*a10};
    if (i0 + 1 < 127)
        *(float2*)&ob[(i0+1)*128 + j0] = float2{base - 2.f*a01, base - 2.f*a11};
}

extern "C" void kernel_launch(void* const* d_in, const int* in_sizes, int n_in,
                              void* d_out, int out_size, void* d_ws, size_t ws_size,
                              hipStream_t stream) {
    const float* x    = (const float*)d_in[0];
    const float* W1   = (const float*)d_in[1];
    const float* b1   = (const float*)d_in[2];
    const float* W2   = (const float*)d_in[3];
    const float* b2   = (const float*)d_in[4];
    const float* Wout = (const float*)d_in[5];
    const float* bout = (const float*)d_in[6];
    float* out = (float*)d_out;

    unsigned short* Yb = (unsigned short*)d_ws;   // 8 MB bf16 (E1 | E2)

    dim3 g1(R_/64, OC/64);       // (64, 16) = 1024 blocks
    k1_mfma<<<g1, 256, 0, stream>>>(x, W1, b1, W2, b2, Yb);

    dim3 g2(16, B_);             // (jt|it, b) = 512 blocks
    k2_tanh<<<g2, 256, 0, stream>>>(Yb, Wout, bout, out);
}

// Round 12
// 118.918 us; speedup vs baseline: 1.0585x; 1.0585x over previous
//
#include <hip/hip_runtime.h>
#include <hip/hip_bf16.h>

#define B_ 32
#define N_ 128
#define D_ 512
#define A_ 512
#define R_ (B_*N_)     // 4096 rows
#define OC 1024        // fused Y cols (E1 | E2)
#define CEXP 2.8853900817779268f   // 2*log2(e)

typedef __attribute__((ext_vector_type(8)))  short frag_ab;   // 8 bf16
typedef __attribute__((ext_vector_type(16))) float frag_c;    // 16 f32 (32x32 acc)

__device__ inline unsigned pack2bf(float a, float b) {
    unsigned ua = __builtin_bit_cast(unsigned, a) + 0x8000u;
    unsigned ub = __builtin_bit_cast(unsigned, b) + 0x8000u;
    return __builtin_amdgcn_perm(ub, ua, 0x07060302);
}
__device__ inline float bf2f_lo(unsigned u){ return __builtin_bit_cast(float, u << 16); }
__device__ inline float bf2f_hi(unsigned u){ return __builtin_bit_cast(float, u & 0xffff0000u); }

// ---------------- Kernel 0: fp32 -> bf16 conversion of X, W1, W2 ----------
__global__ __launch_bounds__(256) void k0_cvt(
    const float* __restrict__ X, const float* __restrict__ W1,
    const float* __restrict__ W2,
    unsigned short* __restrict__ Xb, unsigned short* __restrict__ W1b,
    unsigned short* __restrict__ W2b)
{
    const int NX = R_*D_/8, NW = A_*D_/8;
    int i = blockIdx.x*256 + threadIdx.x;
    const float* src; unsigned short* dst; int off;
    if (i < NX)            { src = X;  dst = Xb;  off = i; }
    else if (i < NX+NW)    { src = W1; dst = W1b; off = i-NX; }
    else if (i < NX+2*NW)  { src = W2; dst = W2b; off = i-NX-NW; }
    else return;
    float4 a = ((const float4*)src)[off*2];
    float4 c = ((const float4*)src)[off*2+1];
    uint4 o;
    o.x = pack2bf(a.x,a.y); o.y = pack2bf(a.z,a.w);
    o.z = pack2bf(c.x,c.y); o.w = pack2bf(c.z,c.w);
    ((uint4*)dst)[off] = o;
}

// ---------------- Kernel 1: Yb = bf16(exp2(C*(X*[W1;W2]^T + [b1;b2]))) ----
// R10-verified: 64x64 tile, BK=64, 4 waves each one 32x32x16 acc, 4 blk/CU.
// LDS [64 rows][8 slots x16B], phys_slot = slot ^ (row&7) both sides.
__global__ __launch_bounds__(256) void k1_mfma(
    const unsigned short* __restrict__ Xb,
    const unsigned short* __restrict__ W1b, const float* __restrict__ b1,
    const unsigned short* __restrict__ W2b, const float* __restrict__ b2,
    unsigned short* __restrict__ Yb)
{
    __shared__ unsigned short As[2][64*64];
    __shared__ unsigned short Bs[2][64*64];

    const int t = threadIdx.x, lane = t&63, wid = t>>6;
    const int wr = wid>>1, wc = wid&1;
    const int row0 = blockIdx.x*64, col0 = blockIdx.y*64;
    const unsigned short* Wb = (col0 < A_) ? W1b : W2b;
    const float* bb = (col0 < A_) ? b1 : b2;
    const int wrow0 = col0 & (A_-1);

    const int sr = t>>2;          // staging row 0..63
    const int ss = (t&3)*2;       // staging slots: ss, ss+1
    const int sf = sr & 7;        // write-side XOR key

    frag_c acc;
#pragma unroll
    for (int r=0;r<16;++r) acc[r] = 0.f;

    const int fr = lane & 31;
    const int hs = lane >> 5;              // k-half
    const int arow = wr*32 + fr, af_f = arow & 7;
    const int brow = wc*32 + fr, bf_f = brow & 7;

    { // prologue: stage K-chunk 0 into buf0
        const unsigned short* px = &Xb[(size_t)(row0 +sr)*D_ + ss*8];
        const unsigned short* pw = &Wb[(size_t)(wrow0+sr)*D_ + ss*8];
        uint4 a0 = *(const uint4*)px, a1 = *(const uint4*)(px+8);
        uint4 b0 = *(const uint4*)pw, b1v = *(const uint4*)(pw+8);
        *(uint4*)&As[0][sr*64 + (( ss   ^sf)<<3)] = a0;
        *(uint4*)&As[0][sr*64 + (((ss+1)^sf)<<3)] = a1;
        *(uint4*)&Bs[0][sr*64 + (( ss   ^sf)<<3)] = b0;
        *(uint4*)&Bs[0][sr*64 + (((ss+1)^sf)<<3)] = b1v;
    }
    __syncthreads();

#pragma unroll
    for (int s = 0; s < 8; ++s) {
        const int cur = s & 1;
        uint4 a0, a1, b0, b1v;
        if (s < 7) {   // early-issue next K-chunk's loads
            const int k0 = (s+1)*64;
            const unsigned short* px = &Xb[(size_t)(row0 +sr)*D_ + k0 + ss*8];
            const unsigned short* pw = &Wb[(size_t)(wrow0+sr)*D_ + k0 + ss*8];
            a0 = *(const uint4*)px; a1 = *(const uint4*)(px+8);
            b0 = *(const uint4*)pw; b1v = *(const uint4*)(pw+8);
        }
        frag_ab af[4], bf[4];
#pragma unroll
        for (int ks=0; ks<4; ++ks) {
            const int slot = ks*2 + hs;
            af[ks] = *(const frag_ab*)&As[cur][arow*64 + ((slot^af_f)<<3)];
            bf[ks] = *(const frag_ab*)&Bs[cur][brow*64 + ((slot^bf_f)<<3)];
        }
#pragma unroll
        for (int ks=0; ks<4; ++ks)
            acc = __builtin_amdgcn_mfma_f32_32x32x16_bf16(af[ks], bf[ks], acc, 0, 0, 0);
        if (s < 7) {   // write-late into the other buffer
            *(uint4*)&As[cur^1][sr*64 + (( ss   ^sf)<<3)] = a0;
            *(uint4*)&As[cur^1][sr*64 + (((ss+1)^sf)<<3)] = a1;
            *(uint4*)&Bs[cur^1][sr*64 + (( ss   ^sf)<<3)] = b0;
            *(uint4*)&Bs[cur^1][sr*64 + (((ss+1)^sf)<<3)] = b1v;
        }
        __syncthreads();
    }

    // epilogue: 32x32 C/D layout col=lane&31, row=(reg&3)+8*(reg>>2)+4*(lane>>5)
    const int cc = col0 + wc*32 + (lane&31);
    const float bias = bb[cc & (A_-1)];
    const int rbase = row0 + wr*32 + 4*(lane>>5);
#pragma unroll
    for (int r=0; r<16; ++r) {
        const int rr = rbase + (r&3) + 8*(r>>2);
        float e = __builtin_amdgcn_exp2f(CEXP*(acc[r] + bias));
        Yb[(size_t)rr*OC + cc] =
            (unsigned short)((__builtin_bit_cast(unsigned, e) + 0x8000u) >> 16);
    }
}

// ---------------- Kernel 2 ----------------
// out[b,i,j] = wsum - 2*sum_a wo[a]/(1+E1[j,a]*E2[i+1,a]) + bout
// Block: 32j x 16i, full a in 2 chunks of 256. 26 KB LDS -> 4 blk/CU,
// 16 waves/CU. bf16 LDS, phys_slot = slot ^ (row>>1) both sides (reads
// <=2-way free). 2j x 1i per thread, reciprocal pairing. Direct out.
#define ACH2 256

__global__ __launch_bounds__(256) void k2_tanh(
    const unsigned short* __restrict__ Yb,
    const float* __restrict__ Wout, const float* __restrict__ bout,
    float* __restrict__ out)
{
    __shared__ unsigned short e1s[32*ACH2];   // 16 KB
    __shared__ unsigned short e2s[16*ACH2];   //  8 KB
    __shared__ float wo[A_];                  //  2 KB
    __shared__ float wsum_s[4];

    const int t  = threadIdx.x;
    const int jt = blockIdx.x;      // 0..3   (32 j each)
    const int it = blockIdx.y;      // 0..7   (16 i each)
    const int b  = blockIdx.z;

    {   // Wout -> LDS + block sum
        float w0 = Wout[t], w1 = Wout[256+t];
        wo[t] = w0; wo[256+t] = w1;
        float s = w0 + w1;
#pragma unroll
        for (int off=32; off>=1; off>>=1) s += __shfl_down(s, off, 64);
        if ((t&63)==0) wsum_s[t>>6] = s;
    }

    const unsigned short* yb = Yb + (size_t)b*N_*OC;
    const int jl = t&15, il = t>>4;

    // staging coordinates
    const int r1 = t>>3,  in1 = t&7;    // e1: row 0..31, 4 slots each
    const int r2 = t>>4,  in2 = t&15;   // e2: row 0..15, 2 slots each
    const int g2 = min(it*16 + r2 + 1, 127);
    const unsigned short* p1 = &yb[(size_t)(jt*32 + r1)*OC];
    const unsigned short* p2 = &yb[(size_t)g2*OC + A_];

    float acc0 = 0.f, acc1 = 0.f;

#pragma unroll
    for (int ch = 0; ch < 2; ++ch) {
        const int abase = ch*ACH2;
        if (ch) __syncthreads();    // readers of previous chunk done
#pragma unroll
        for (int q=0; q<4; ++q) {   // e1: 4 x uint4
            const int s = q*8 + in1;
            uint4 v = *(const uint4*)(p1 + abase + s*8);
            *(uint4*)&e1s[r1*ACH2 + ((s ^ (r1>>1))<<3)] = v;
        }
#pragma unroll
        for (int q=0; q<2; ++q) {   // e2: 2 x uint4
            const int s = q*16 + in2;
            uint4 v = *(const uint4*)(p2 + abase + s*8);
            *(uint4*)&e2s[r2*ACH2 + ((s ^ (r2>>1))<<3)] = v;
        }
        __syncthreads();

        const unsigned short* ru0 = &e1s[(2*jl  )*ACH2];
        const unsigned short* ru1 = &e1s[(2*jl+1)*ACH2];
        const unsigned short* rv  = &e2s[il*ACH2];
        const int kv = il>>1;

#pragma unroll 4
        for (int c8=0; c8<32; ++c8) {
            uint4 U0 = *(const uint4*)&ru0[(c8^jl)<<3];
            uint4 U1 = *(const uint4*)&ru1[(c8^jl)<<3];
            uint4 V  = *(const uint4*)&rv [(c8^kv)<<3];
            float4 wa = *(const float4*)&wo[abase + c8*8];
            float4 wb = *(const float4*)&wo[abase + c8*8 + 4];
            float u0[8], u1[8], vv[8];
            u0[0]=bf2f_lo(U0.x); u0[1]=bf2f_hi(U0.x); u0[2]=bf2f_lo(U0.y); u0[3]=bf2f_hi(U0.y);
            u0[4]=bf2f_lo(U0.z); u0[5]=bf2f_hi(U0.z); u0[6]=bf2f_lo(U0.w); u0[7]=bf2f_hi(U0.w);
            u1[0]=bf2f_lo(U1.x); u1[1]=bf2f_hi(U1.x); u1[2]=bf2f_lo(U1.y); u1[3]=bf2f_hi(U1.y);
            u1[4]=bf2f_lo(U1.z); u1[5]=bf2f_hi(U1.z); u1[6]=bf2f_lo(U1.w); u1[7]=bf2f_hi(U1.w);
            vv[0]=bf2f_lo(V.x);  vv[1]=bf2f_hi(V.x);  vv[2]=bf2f_lo(V.y);  vv[3]=bf2f_hi(V.y);
            vv[4]=bf2f_lo(V.z);  vv[5]=bf2f_hi(V.z);  vv[6]=bf2f_lo(V.w);  vv[7]=bf2f_hi(V.w);
            float wf[8] = {wa.x, wa.y, wa.z, wa.w, wb.x, wb.y, wb.z, wb.w};
#pragma unroll
            for (int p=0; p<4; ++p) {
                const int e0 = 2*p, e1i = 2*p+1;
                { float r=fmaf(u0[e0],vv[e0],1.f), s=fmaf(u0[e1i],vv[e1i],1.f);
                  acc0 = fmaf(fmaf(wf[e0],s,wf[e1i]*r), __builtin_amdgcn_rcpf(r*s), acc0); }
                { float r=fmaf(u1[e0],vv[e0],1.f), s=fmaf(u1[e1i],vv[e1i],1.f);
                  acc1 = fmaf(fmaf(wf[e0],s,wf[e1i]*r), __builtin_amdgcn_rcpf(r*s), acc1); }
            }
        }
    }

    const float base = wsum_s[0]+wsum_s[1]+wsum_s[2]+wsum_s[3] + bout[0];
    const int i0 = it*16 + il;          // x2-row = i0+1
    const int j0 = jt*32 + 2*jl;
    if (i0 < 127)
        *(float2*)&out[((size_t)(b*127) + i0)*128 + j0] =
            float2{base - 2.f*acc0, base - 2.f*acc1};
}

extern "C" void kernel_launch(void* const* d_in, const int* in_sizes, int n_in,
                              void* d_out, int out_size, void* d_ws, size_t ws_size,
                              hipStream_t stream) {
    const float* x    = (const float*)d_in[0];
    const float* W1   = (const float*)d_in[1];
    const float* b1   = (const float*)d_in[2];
    const float* W2   = (const float*)d_in[3];
    const float* b2   = (const float*)d_in[4];
    const float* Wout = (const float*)d_in[5];
    const float* bout = (const float*)d_in[6];
    float* out = (float*)d_out;

    char* ws = (char*)d_ws;
    unsigned short* Yb  = (unsigned short*)ws;                              // 8 MB
    unsigned short* Xb  = (unsigned short*)(ws + (8u<<20));                 // 4 MB
    unsigned short* W1b = (unsigned short*)(ws + (12u<<20));                // 512 KB
    unsigned short* W2b = (unsigned short*)(ws + (12u<<20) + (1u<<19));     // 512 KB

    k0_cvt<<<1280, 256, 0, stream>>>(x, W1, W2, Xb, W1b, W2b);

    dim3 g1(R_/64, OC/64);       // (64, 16) = 1024 blocks
    k1_mfma<<<g1, 256, 0, stream>>>(Xb, W1b, b1, W2b, b2, Yb);

    dim3 g2(4, 8, B_);           // (jt, it, b) = 1024 blocks, 4 blk/CU
    k2_tanh<<<g2, 256, 0, stream>>>(Yb, Wout, bout, out);
}